// Round 5
// baseline (235.067 us; speedup 1.0000x reference)
//
#include <hip/hip_runtime.h>
#include <hip/hip_cooperative_groups.h>

#define B_ 4
#define T_ 2048
#define C_ 1024
#define H_ 64
#define M_ (B_*T_)

typedef __bf16 bf16x8 __attribute__((ext_vector_type(8)));
typedef float f32x4 __attribute__((ext_vector_type(4)));
typedef short short8 __attribute__((ext_vector_type(8)));
typedef short short4v __attribute__((ext_vector_type(4)));
typedef float float4v __attribute__((ext_vector_type(4)));

static __device__ __forceinline__ f32x4 mfma16(bf16x8 a, bf16x8 b, f32x4 c) {
    return __builtin_amdgcn_mfma_f32_16x16x32_bf16(a, b, c, 0, 0, 0);
}
static __device__ __forceinline__ unsigned short f2bfu(float f) {
    return __builtin_bit_cast(unsigned short, (__bf16)f);
}

struct SmemAttn {
    unsigned short plds[8][16][72];
    float olds[8][16][64];
    float mlds[8][16];
    float llds[8][16];
};
struct SmemProj {
    float red[2][12][64][4];
    unsigned short stage[3][16][72];
};
union alignas(16) Smem { SmemAttn a; SmemProj p; };

// ---------------------------------------------------------------------------
// One cooperative kernel, 512 blocks x 512 threads (2 blocks/CU co-resident:
// LDS 52KB, VGPR<=128 via launch_bounds).  mode==3: all phases + grid.sync;
// mode 0/1/2: single phase (fallback path where kernel boundaries sync).
//
// Phase A: repack Wk|Wq|Wv -> bf16 B-fragments Wtf (frag f=kk*12+n, lane l
//   holds W[kk*32+(l>>4)*8+j][n*16+(l&15)]; n 0-3 K, 4-7 Q(*1/32), 8-11 V).
// Phase B: QKV projection, 16 tokens/block, 8 waves = 2 K-halves x 4 col-sets,
//   LDS reduce + transpose epilogue writing fragment-order kbuf/qfb/vbuf:
//   kbuf[b*64+jt][kk][nn][lane][8] : K[b, jt*32+nn*16+(l&15), kk*32+(l>>4)*8+j]
//   qfb [tile16][kk][lane][8]      : Q[tile16*16+(l&15), kk*32+(l>>4)*8+j]
//   vbuf[b*64+jt][nh][lane][8]     : V[b, jt*32+(l>>4)*8+j, nh*16+(l&15)]
// Phase C: causal flash attn, swapped QK^T (lane owns q-row lm), 8 waves
//   stripe 64-key tiles, online softmax, P repack via per-wave LDS.
// ---------------------------------------------------------------------------
__global__ __launch_bounds__(512, 4) void mega_kernel(
        const float* __restrict__ x,
        const float* __restrict__ Wk, const float* __restrict__ Wq,
        const float* __restrict__ Wv,
        unsigned short* __restrict__ ws, float* __restrict__ out, int mode) {
    __shared__ Smem sm;
    unsigned short* Wtf  = ws;
    unsigned short* kbuf = ws + 196608;
    unsigned short* qfb  = kbuf + 524288;
    unsigned short* vbuf = qfb + 524288;

    int tid = threadIdx.x;
    int bid = blockIdx.x;
    int l = tid & 63, lm = l & 15, lg = l >> 4;
    int w = tid >> 6;

    // ---------------- phase A: W repack ----------------
    if ((mode == 3 || mode == 0) && bid < 48) {
        int t = bid * 512 + tid;
        int f = t >> 6, la = t & 63;
        int n = f % 12, kk = f / 12;
        int sel = n >> 2;
        int wcol = (n & 3) * 16 + (la & 15);
        int kbase = kk * 32 + (la >> 4) * 8;
        const float* W = (sel == 0) ? Wk : ((sel == 1) ? Wq : Wv);
        float scale = (sel == 1) ? 0.03125f : 1.0f;
        unsigned short* dst = Wtf + f * 512 + la * 8;
#pragma unroll
        for (int j = 0; j < 8; ++j)
            dst[j] = f2bfu(W[(kbase + j) * 64 + wcol] * scale);
    }
    if (mode == 3) cooperative_groups::this_grid().sync();

    // ---------------- phase B: projection ----------------
    if (mode == 3 || mode == 1) {
        int r0 = bid * 16;
        int khalf = w >> 2;
        int c3 = (w & 3) * 3;
        f32x4 acc[3];
#pragma unroll
        for (int nn = 0; nn < 3; ++nn) acc[nn] = f32x4{0.f, 0.f, 0.f, 0.f};

        const float* xp = x + (r0 + lm) * C_ + khalf * 512 + lg * 8;
        const unsigned short* wp = Wtf + (khalf * 16 * 12 + c3) * 512 + l * 8;

        float4v a0 = *(const float4v*)(xp);
        float4v a1 = *(const float4v*)(xp + 4);
        short8 b0 = *(const short8*)(wp);
        short8 b1 = *(const short8*)(wp + 512);
        short8 b2 = *(const short8*)(wp + 1024);
        for (int kk = 0; kk < 15; ++kk) {
            xp += 32; wp += 12 * 512;
            float4v na0 = *(const float4v*)(xp);
            float4v na1 = *(const float4v*)(xp + 4);
            short8 nb0 = *(const short8*)(wp);
            short8 nb1 = *(const short8*)(wp + 512);
            short8 nb2 = *(const short8*)(wp + 1024);
            bf16x8 af;
#pragma unroll
            for (int j = 0; j < 4; ++j) { af[j] = (__bf16)a0[j]; af[4 + j] = (__bf16)a1[j]; }
            acc[0] = mfma16(af, __builtin_bit_cast(bf16x8, b0), acc[0]);
            acc[1] = mfma16(af, __builtin_bit_cast(bf16x8, b1), acc[1]);
            acc[2] = mfma16(af, __builtin_bit_cast(bf16x8, b2), acc[2]);
            a0 = na0; a1 = na1; b0 = nb0; b1 = nb1; b2 = nb2;
        }
        {
            bf16x8 af;
#pragma unroll
            for (int j = 0; j < 4; ++j) { af[j] = (__bf16)a0[j]; af[4 + j] = (__bf16)a1[j]; }
            acc[0] = mfma16(af, __builtin_bit_cast(bf16x8, b0), acc[0]);
            acc[1] = mfma16(af, __builtin_bit_cast(bf16x8, b1), acc[1]);
            acc[2] = mfma16(af, __builtin_bit_cast(bf16x8, b2), acc[2]);
        }
#pragma unroll
        for (int nn = 0; nn < 3; ++nn)
            *(f32x4*)&sm.p.red[khalf][c3 + nn][l][0] = acc[nn];
        __syncthreads();

        // combine K-halves, stage row-major bf16 tiles [K|Q|V][16][72]
        for (int idx = tid; idx < 768; idx += 512) {
            int tile = idx >> 6, l2 = idx & 63, lm2 = l2 & 15, lg2 = l2 >> 4;
            f32x4 s0 = *(const f32x4*)&sm.p.red[0][tile][l2][0];
            f32x4 s1 = *(const f32x4*)&sm.p.red[1][tile][l2][0];
            int sel = tile >> 2, colb = (tile & 3) * 16 + lm2;
#pragma unroll
            for (int i = 0; i < 4; ++i)
                sm.p.stage[sel][lg2 * 4 + i][colb] = f2bfu(s0[i] + s1[i]);
        }
        __syncthreads();

        int bq = bid >> 7;
        int jt = (bid & 127) >> 1;
        int nn = bid & 1;
        int base = (bq * 64 + jt) * 2048;
        if (w < 2) {                 // K fragments, kk = w
            short8 v = *(const short8*)&sm.p.stage[0][lm][w * 32 + lg * 8];
            *(short8*)(kbuf + base + w * 1024 + nn * 512 + l * 8) = v;
        } else if (w < 4) {          // Q fragments, kk = w-2
            int kkq = w - 2;
            short8 v = *(const short8*)&sm.p.stage[1][lm][kkq * 32 + lg * 8];
            *(short8*)(qfb + bid * 1024 + kkq * 512 + l * 8) = v;
        } else if (l < 32) {         // V half-fragments, nh = w-4
            int nh = w - 4;
            short8 v;
#pragma unroll
            for (int j = 0; j < 8; ++j)
                v[j] = (short)sm.p.stage[2][(l >> 4) * 8 + j][nh * 16 + (l & 15)];
            *(short8*)(vbuf + base + nh * 512 + nn * 256 + l * 8) = v;
        }
    }
    if (mode == 3) cooperative_groups::this_grid().sync();

    // ---------------- phase C: attention ----------------
    if (!(mode == 3 || mode == 2)) return;
    {
        int xcd = bid & 7, ii = bid >> 3;
        int b = xcd >> 1;
        int qtl = ii * 2 + (xcd & 1);
        int q0 = (127 - qtl) * 16;

        bf16x8 qf[2];
#pragma unroll
        for (int kk = 0; kk < 2; ++kk)
            qf[kk] = __builtin_bit_cast(bf16x8,
                *(const short8*)(qfb + (b * 128 + (q0 >> 4)) * 1024 + kk * 512 + l * 8));

        f32x4 of[4];
#pragma unroll
        for (int nh = 0; nh < 4; ++nh) of[nh] = f32x4{0.f, 0.f, 0.f, 0.f};
        float mrun = -1e30f, lrun = 0.f;

        int nj = q0 / 64 + 1;

        for (int J = w; J < nj; J += 8) {
            f32x4 s[4];
#pragma unroll
            for (int n = 0; n < 4; ++n) s[n] = f32x4{0.f, 0.f, 0.f, 0.f};
#pragma unroll
            for (int kk = 0; kk < 2; ++kk) {
#pragma unroll
                for (int n = 0; n < 4; ++n) {
                    const unsigned short* kp = kbuf +
                        (((b * 64 + 2 * J + (n >> 1)) * 2 + kk) * 2 + (n & 1)) * 512 + l * 8;
                    s[n] = mfma16(__builtin_bit_cast(bf16x8, *(const short8*)kp), qf[kk], s[n]);
                }
            }
            if (J == nj - 1) {
                int qr = q0 + lm;
#pragma unroll
                for (int n = 0; n < 4; ++n) {
                    int kc0 = J * 64 + (n >> 1) * 32 + (n & 1) * 16 + lg * 4;
#pragma unroll
                    for (int i = 0; i < 4; ++i)
                        if (kc0 + i > qr) s[n][i] = -1e30f;
                }
            }
            float pm0 = fmaxf(fmaxf(s[0][0], s[0][1]), fmaxf(s[0][2], s[0][3]));
            float pm1 = fmaxf(fmaxf(s[1][0], s[1][1]), fmaxf(s[1][2], s[1][3]));
            float pm2 = fmaxf(fmaxf(s[2][0], s[2][1]), fmaxf(s[2][2], s[2][3]));
            float pm3 = fmaxf(fmaxf(s[3][0], s[3][1]), fmaxf(s[3][2], s[3][3]));
            float pm = fmaxf(fmaxf(pm0, pm1), fmaxf(pm2, pm3));
            pm = fmaxf(pm, __shfl_xor(pm, 16, 64));
            pm = fmaxf(pm, __shfl_xor(pm, 32, 64));
            float mn = fmaxf(mrun, pm);
            float al = __expf(mrun - mn);
            float rsn[4];
#pragma unroll
            for (int n = 0; n < 4; ++n) {
                float e0 = __expf(s[n][0] - mn), e1 = __expf(s[n][1] - mn);
                float e2 = __expf(s[n][2] - mn), e3 = __expf(s[n][3] - mn);
                s[n][0] = e0; s[n][1] = e1; s[n][2] = e2; s[n][3] = e3;
                rsn[n] = (e0 + e1) + (e2 + e3);
            }
            float rs = (rsn[0] + rsn[1]) + (rsn[2] + rsn[3]);
            rs += __shfl_xor(rs, 16, 64);
            rs += __shfl_xor(rs, 32, 64);
            lrun = lrun * al + rs;
            mrun = mn;
            float alv[4];
#pragma unroll
            for (int i = 0; i < 4; ++i) alv[i] = __shfl(al, lg * 4 + i, 64);
#pragma unroll
            for (int nh = 0; nh < 4; ++nh)
#pragma unroll
                for (int i = 0; i < 4; ++i) of[nh][i] *= alv[i];

#pragma unroll
            for (int n = 0; n < 4; ++n) {
                short4v pv;
#pragma unroll
                for (int i = 0; i < 4; ++i) pv[i] = (short)f2bfu(s[n][i]);
                *(short4v*)(&sm.a.plds[w][lm][(n >> 1) * 32 + (n & 1) * 16 + lg * 4]) = pv;
            }
            bf16x8 pf[2];
#pragma unroll
            for (int ks = 0; ks < 2; ++ks)
                pf[ks] = __builtin_bit_cast(bf16x8,
                    *(const short8*)(&sm.a.plds[w][lm][ks * 32 + lg * 8]));
#pragma unroll
            for (int nh = 0; nh < 4; ++nh) {
#pragma unroll
                for (int ks = 0; ks < 2; ++ks) {
                    const unsigned short* vp = vbuf +
                        ((b * 64 + 2 * J + ks) * 4 + nh) * 512 + l * 8;
                    of[nh] = mfma16(pf[ks], __builtin_bit_cast(bf16x8, *(const short8*)vp), of[nh]);
                }
            }
        }

#pragma unroll
        for (int nh = 0; nh < 4; ++nh)
#pragma unroll
            for (int i = 0; i < 4; ++i)
                sm.a.olds[w][lg * 4 + i][nh * 16 + lm] = of[nh][i];
        if (l < 16) {
            sm.a.mlds[w][l] = mrun;
            sm.a.llds[w][l] = lrun;
        }
        __syncthreads();

        int row = tid >> 5;
        int c0 = tid & 31;
        float mw[8];
#pragma unroll
        for (int u = 0; u < 8; ++u) mw[u] = sm.a.mlds[u][row];
        float M = fmaxf(fmaxf(fmaxf(mw[0], mw[1]), fmaxf(mw[2], mw[3])),
                        fmaxf(fmaxf(mw[4], mw[5]), fmaxf(mw[6], mw[7])));
        float ew[8];
        float L = 0.f;
#pragma unroll
        for (int u = 0; u < 8; ++u) { ew[u] = __expf(mw[u] - M); L += sm.a.llds[u][row] * ew[u]; }
        float invL = 1.0f / L;
#pragma unroll
        for (int h = 0; h < 2; ++h) {
            int col = c0 + h * 32;
            float o = 0.f;
#pragma unroll
            for (int u = 0; u < 8; ++u) o += sm.a.olds[u][row][col] * ew[u];
            out[(b * T_ + q0 + row) * H_ + col] = o * invL;
        }
    }
}

extern "C" void kernel_launch(void* const* d_in, const int* in_sizes, int n_in,
                              void* d_out, int out_size, void* d_ws, size_t ws_size,
                              hipStream_t stream) {
    const float* x  = (const float*)d_in[0];
    const float* Wk = (const float*)d_in[1];
    const float* Wq = (const float*)d_in[2];
    const float* Wv = (const float*)d_in[3];
    unsigned short* ws = (unsigned short*)d_ws;
    float* o = (float*)d_out;

    int mode = 3;
    void* args[] = {(void*)&x, (void*)&Wk, (void*)&Wq, (void*)&Wv,
                    (void*)&ws, (void*)&o, (void*)&mode};
    hipError_t rc = hipLaunchCooperativeKernel(
        reinterpret_cast<void*>(mega_kernel), dim3(512), dim3(512), args, 0, stream);
    if (rc != hipSuccess) {
        // fallback: phase-split normal launches (kernel boundaries = global sync)
        mega_kernel<<<dim3(512), dim3(512), 0, stream>>>(x, Wk, Wq, Wv, ws, o, 0);
        mega_kernel<<<dim3(512), dim3(512), 0, stream>>>(x, Wk, Wq, Wv, ws, o, 1);
        mega_kernel<<<dim3(512), dim3(512), 0, stream>>>(x, Wk, Wq, Wv, ws, o, 2);
    }
}

// Round 6
// 103.952 us; speedup vs baseline: 2.2613x; 2.2613x over previous
//
#include <hip/hip_runtime.h>

#define B_ 4
#define T_ 2048
#define C_ 1024
#define H_ 64
#define M_ (B_*T_)

typedef __bf16 bf16x8 __attribute__((ext_vector_type(8)));
typedef float f32x4 __attribute__((ext_vector_type(4)));
typedef short short8 __attribute__((ext_vector_type(8)));
typedef short short4v __attribute__((ext_vector_type(4)));
typedef float float4v __attribute__((ext_vector_type(4)));

static __device__ __forceinline__ f32x4 mfma16(bf16x8 a, bf16x8 b, f32x4 c) {
    return __builtin_amdgcn_mfma_f32_16x16x32_bf16(a, b, c, 0, 0, 0);
}
static __device__ __forceinline__ unsigned short f2bfu(float f) {
    return __builtin_bit_cast(unsigned short, (__bf16)f);
}

// ---------------------------------------------------------------------------
// Kernel 1: repack Wk|Wq|Wv (fp32 [1024][64]) -> bf16 MFMA B-fragments.
// Wtf frag f = kk*12 + n; lane l holds W[kk*32+(l>>4)*8+j][n*16+(l&15)].
// n 0-3: Wk, 4-7: Wq (*1/32), 8-11: Wv.
// ---------------------------------------------------------------------------
__global__ __launch_bounds__(256) void wconv_kernel(const float* __restrict__ Wk,
                                                    const float* __restrict__ Wq,
                                                    const float* __restrict__ Wv,
                                                    unsigned short* __restrict__ Wtf) {
    int t = blockIdx.x * 256 + threadIdx.x;
    int f = t >> 6;
    int l = t & 63;
    int n = f % 12, kk = f / 12;
    int sel = n >> 2;
    int wcol = (n & 3) * 16 + (l & 15);
    int kbase = kk * 32 + (l >> 4) * 8;
    const float* W = (sel == 0) ? Wk : ((sel == 1) ? Wq : Wv);
    float scale = (sel == 1) ? 0.03125f : 1.0f;
    unsigned short* dst = Wtf + f * 512 + l * 8;
#pragma unroll
    for (int j = 0; j < 8; ++j)
        dst[j] = f2bfu(W[(kbase + j) * 64 + wcol] * scale);
}

// ---------------------------------------------------------------------------
// Kernel 2: QKV projection, 512 blocks x 512 thr (8 waves = 2 K-halves x 4
// col-sets -> 4 waves/SIMD). 16 serial K-steps/wave, 1-deep prefetch, LDS
// reduce of the two K-halves, then fragment-order epilogue (kvconv fused):
//   kbuf[b*64+jt][kk][nn][lane][8] : K[b, jt*32+nn*16+(l&15), kk*32+(l>>4)*8+j]
//   qfb [b*128+t16][kk][lane][8]   : Q[b, t16*16+(l&15), kk*32+(l>>4)*8+j]
//   vbuf[b*64+jt][nh][lane][8]     : V[b, jt*32+(l>>4)*8+j, nh*16+(l&15)]
// ---------------------------------------------------------------------------
struct SmemProj {
    float red[2][12][64][4];
    unsigned short stage[3][16][72];
};

__global__ __launch_bounds__(512) void proj_kernel(const float* __restrict__ x,
                                                   const unsigned short* __restrict__ Wtf,
                                                   unsigned short* __restrict__ kbuf,
                                                   unsigned short* __restrict__ qfb,
                                                   unsigned short* __restrict__ vbuf) {
    __shared__ SmemProj sm;
    int tid = threadIdx.x;
    int bid = blockIdx.x;
    int l = tid & 63, lm = l & 15, lg = l >> 4;
    int w = tid >> 6;

    int r0 = bid * 16;
    int khalf = w >> 2;
    int c3 = (w & 3) * 3;
    f32x4 acc[3];
#pragma unroll
    for (int nn = 0; nn < 3; ++nn) acc[nn] = f32x4{0.f, 0.f, 0.f, 0.f};

    const float* xp = x + (r0 + lm) * C_ + khalf * 512 + lg * 8;
    const unsigned short* wp = Wtf + (khalf * 16 * 12 + c3) * 512 + l * 8;

    float4v a0 = *(const float4v*)(xp);
    float4v a1 = *(const float4v*)(xp + 4);
    short8 b0 = *(const short8*)(wp);
    short8 b1 = *(const short8*)(wp + 512);
    short8 b2 = *(const short8*)(wp + 1024);
    for (int kk = 0; kk < 15; ++kk) {
        xp += 32; wp += 12 * 512;
        float4v na0 = *(const float4v*)(xp);
        float4v na1 = *(const float4v*)(xp + 4);
        short8 nb0 = *(const short8*)(wp);
        short8 nb1 = *(const short8*)(wp + 512);
        short8 nb2 = *(const short8*)(wp + 1024);
        bf16x8 af;
#pragma unroll
        for (int j = 0; j < 4; ++j) { af[j] = (__bf16)a0[j]; af[4 + j] = (__bf16)a1[j]; }
        acc[0] = mfma16(af, __builtin_bit_cast(bf16x8, b0), acc[0]);
        acc[1] = mfma16(af, __builtin_bit_cast(bf16x8, b1), acc[1]);
        acc[2] = mfma16(af, __builtin_bit_cast(bf16x8, b2), acc[2]);
        a0 = na0; a1 = na1; b0 = nb0; b1 = nb1; b2 = nb2;
    }
    {
        bf16x8 af;
#pragma unroll
        for (int j = 0; j < 4; ++j) { af[j] = (__bf16)a0[j]; af[4 + j] = (__bf16)a1[j]; }
        acc[0] = mfma16(af, __builtin_bit_cast(bf16x8, b0), acc[0]);
        acc[1] = mfma16(af, __builtin_bit_cast(bf16x8, b1), acc[1]);
        acc[2] = mfma16(af, __builtin_bit_cast(bf16x8, b2), acc[2]);
    }
#pragma unroll
    for (int nn = 0; nn < 3; ++nn)
        *(f32x4*)&sm.red[khalf][c3 + nn][l][0] = acc[nn];
    __syncthreads();

    // combine K-halves, stage row-major bf16 tiles [K|Q|V][16 rows][72]
    for (int idx = tid; idx < 768; idx += 512) {
        int tile = idx >> 6, l2 = idx & 63, lm2 = l2 & 15, lg2 = l2 >> 4;
        f32x4 s0 = *(const f32x4*)&sm.red[0][tile][l2][0];
        f32x4 s1 = *(const f32x4*)&sm.red[1][tile][l2][0];
        int sel = tile >> 2, colb = (tile & 3) * 16 + lm2;
#pragma unroll
        for (int i = 0; i < 4; ++i)
            sm.stage[sel][lg2 * 4 + i][colb] = f2bfu(s0[i] + s1[i]);
    }
    __syncthreads();

    int bq = bid >> 7;
    int jt = (bid & 127) >> 1;
    int nn = bid & 1;
    int base = (bq * 64 + jt) * 2048;
    if (w < 2) {                 // K fragments, kk = w
        short8 v = *(const short8*)&sm.stage[0][lm][w * 32 + lg * 8];
        *(short8*)(kbuf + base + w * 1024 + nn * 512 + l * 8) = v;
    } else if (w < 4) {          // Q fragments, kk = w-2
        int kkq = w - 2;
        short8 v = *(const short8*)&sm.stage[1][lm][kkq * 32 + lg * 8];
        *(short8*)(qfb + bid * 1024 + kkq * 512 + l * 8) = v;
    } else if (l < 32) {         // V half-fragments, nh = w-4
        int nh = w - 4;
        short8 v;
#pragma unroll
        for (int j = 0; j < 8; ++j)
            v[j] = (short)sm.stage[2][(l >> 4) * 8 + j][nh * 16 + (l & 15)];
        *(short8*)(vbuf + base + nh * 512 + nn * 256 + l * 8) = v;
    }
}

// ---------------------------------------------------------------------------
// Kernel 3: causal flash attention, swapped QK^T (lane owns q-row lm). 8 waves
// stripe 64-key tiles; online softmax; P repack via per-wave LDS. Block pair
// (bid, bid+256) lands on the same CU -> q-tiles (127-v, v): per-CU work is
// constant (~2032 keys). Q pre-scaled by 1/32 via Wq.
// ---------------------------------------------------------------------------
struct SmemAttn {
    unsigned short plds[8][16][72];
    float olds[8][16][64];
    float mlds[8][16];
    float llds[8][16];
};

__global__ __launch_bounds__(512) void attn_kernel(const unsigned short* __restrict__ kbuf,
                                                   const unsigned short* __restrict__ qfb,
                                                   const unsigned short* __restrict__ vbuf,
                                                   float* __restrict__ out) {
    __shared__ SmemAttn sm;
    int tid = threadIdx.x;
    int l = tid & 63, lm = l & 15, lg = l >> 4;
    int w = tid >> 6;
    int bid = blockIdx.x;
    int hi = bid >> 8, lo = bid & 255;
    int b = lo & 3;
    int v = lo >> 2;                            // 0..63
    int qtl = hi ? v : (127 - v);               // big-work bids first
    int q0 = qtl * 16;

    bf16x8 qf[2];
#pragma unroll
    for (int kk = 0; kk < 2; ++kk)
        qf[kk] = __builtin_bit_cast(bf16x8,
            *(const short8*)(qfb + (b * 128 + qtl) * 1024 + kk * 512 + l * 8));

    f32x4 of[4];                                // of[nh][i] = O[q0+lg*4+i][nh*16+lm]
#pragma unroll
    for (int nh = 0; nh < 4; ++nh) of[nh] = f32x4{0.f, 0.f, 0.f, 0.f};
    float mrun = -1e30f, lrun = 0.f;            // per q-row = lm

    int nj = q0 / 64 + 1;

    for (int J = w; J < nj; J += 8) {
        f32x4 s[4];
#pragma unroll
        for (int n = 0; n < 4; ++n) s[n] = f32x4{0.f, 0.f, 0.f, 0.f};
#pragma unroll
        for (int kk = 0; kk < 2; ++kk) {
#pragma unroll
            for (int n = 0; n < 4; ++n) {
                const unsigned short* kp = kbuf +
                    (((b * 64 + 2 * J + (n >> 1)) * 2 + kk) * 2 + (n & 1)) * 512 + l * 8;
                s[n] = mfma16(__builtin_bit_cast(bf16x8, *(const short8*)kp), qf[kk], s[n]);
            }
        }
        if (J == nj - 1) {                      // diagonal tile: mask key > q
            int qr = q0 + lm;
#pragma unroll
            for (int n = 0; n < 4; ++n) {
                int kc0 = J * 64 + (n >> 1) * 32 + (n & 1) * 16 + lg * 4;
#pragma unroll
                for (int i = 0; i < 4; ++i)
                    if (kc0 + i > qr) s[n][i] = -1e30f;
            }
        }
        float pm0 = fmaxf(fmaxf(s[0][0], s[0][1]), fmaxf(s[0][2], s[0][3]));
        float pm1 = fmaxf(fmaxf(s[1][0], s[1][1]), fmaxf(s[1][2], s[1][3]));
        float pm2 = fmaxf(fmaxf(s[2][0], s[2][1]), fmaxf(s[2][2], s[2][3]));
        float pm3 = fmaxf(fmaxf(s[3][0], s[3][1]), fmaxf(s[3][2], s[3][3]));
        float pm = fmaxf(fmaxf(pm0, pm1), fmaxf(pm2, pm3));
        pm = fmaxf(pm, __shfl_xor(pm, 16, 64));
        pm = fmaxf(pm, __shfl_xor(pm, 32, 64));
        float mn = fmaxf(mrun, pm);
        float al = __expf(mrun - mn);
        float rsn[4];
#pragma unroll
        for (int n = 0; n < 4; ++n) {
            float e0 = __expf(s[n][0] - mn), e1 = __expf(s[n][1] - mn);
            float e2 = __expf(s[n][2] - mn), e3 = __expf(s[n][3] - mn);
            s[n][0] = e0; s[n][1] = e1; s[n][2] = e2; s[n][3] = e3;
            rsn[n] = (e0 + e1) + (e2 + e3);
        }
        float rs = (rsn[0] + rsn[1]) + (rsn[2] + rsn[3]);
        rs += __shfl_xor(rs, 16, 64);
        rs += __shfl_xor(rs, 32, 64);
        lrun = lrun * al + rs;
        mrun = mn;
        float alv[4];
#pragma unroll
        for (int i = 0; i < 4; ++i) alv[i] = __shfl(al, lg * 4 + i, 64);
#pragma unroll
        for (int nh = 0; nh < 4; ++nh)
#pragma unroll
            for (int i = 0; i < 4; ++i) of[nh][i] *= alv[i];

        // P repack: write P[q=lm][key] short4 runs, read A-frag b128 (same wave)
#pragma unroll
        for (int n = 0; n < 4; ++n) {
            short4v pv;
#pragma unroll
            for (int i = 0; i < 4; ++i) pv[i] = (short)f2bfu(s[n][i]);
            *(short4v*)(&sm.plds[w][lm][(n >> 1) * 32 + (n & 1) * 16 + lg * 4]) = pv;
        }
        bf16x8 pf[2];
#pragma unroll
        for (int ks = 0; ks < 2; ++ks)
            pf[ks] = __builtin_bit_cast(bf16x8,
                *(const short8*)(&sm.plds[w][lm][ks * 32 + lg * 8]));
#pragma unroll
        for (int nh = 0; nh < 4; ++nh) {
#pragma unroll
            for (int ks = 0; ks < 2; ++ks) {
                const unsigned short* vp = vbuf +
                    ((b * 64 + 2 * J + ks) * 4 + nh) * 512 + l * 8;
                of[nh] = mfma16(pf[ks], __builtin_bit_cast(bf16x8, *(const short8*)vp), of[nh]);
            }
        }
    }

    // stash per-wave state, merge across the 8 waves
#pragma unroll
    for (int nh = 0; nh < 4; ++nh)
#pragma unroll
        for (int i = 0; i < 4; ++i)
            sm.olds[w][lg * 4 + i][nh * 16 + lm] = of[nh][i];
    if (l < 16) {
        sm.mlds[w][l] = mrun;
        sm.llds[w][l] = lrun;
    }
    __syncthreads();

    int row = tid >> 5;
    int c0 = tid & 31;
    float mw[8];
#pragma unroll
    for (int u = 0; u < 8; ++u) mw[u] = sm.mlds[u][row];
    float M = fmaxf(fmaxf(fmaxf(mw[0], mw[1]), fmaxf(mw[2], mw[3])),
                    fmaxf(fmaxf(mw[4], mw[5]), fmaxf(mw[6], mw[7])));
    float ew[8];
    float L = 0.f;
#pragma unroll
    for (int u = 0; u < 8; ++u) { ew[u] = __expf(mw[u] - M); L += sm.llds[u][row] * ew[u]; }
    float invL = 1.0f / L;
#pragma unroll
    for (int h = 0; h < 2; ++h) {
        int col = c0 + h * 32;
        float o = 0.f;
#pragma unroll
        for (int u = 0; u < 8; ++u) o += sm.olds[u][row][col] * ew[u];
        out[(b * T_ + q0 + row) * H_ + col] = o * invL;
    }
}

extern "C" void kernel_launch(void* const* d_in, const int* in_sizes, int n_in,
                              void* d_out, int out_size, void* d_ws, size_t ws_size,
                              hipStream_t stream) {
    const float* x  = (const float*)d_in[0];
    const float* Wk = (const float*)d_in[1];
    const float* Wq = (const float*)d_in[2];
    const float* Wv = (const float*)d_in[3];
    float* out = (float*)d_out;

    unsigned short* ws   = (unsigned short*)d_ws;
    unsigned short* Wtf  = ws;                       // 384*512
    unsigned short* kbuf = Wtf + 196608;             // 8192*64
    unsigned short* qfb  = kbuf + 524288;            // 8192*64
    unsigned short* vbuf = qfb + 524288;             // 8192*64

    wconv_kernel<<<dim3(96), dim3(256), 0, stream>>>(Wk, Wq, Wv, Wtf);
    proj_kernel<<<dim3(512), dim3(512), 0, stream>>>(x, Wtf, kbuf, qfb, vbuf);
    attn_kernel<<<dim3(512), dim3(512), 0, stream>>>(kbuf, qfb, vbuf, out);
}